// Round 1
// baseline (96.587 us; speedup 1.0000x reference)
//
#include <hip/hip_runtime.h>
#include <math.h>

#define GRIDK   5
#define DEG     3
#define NC      8          // GRID + DEG
#define IN_DIM  4
#define HID     4
#define NKNOT   13         // 3 pad + 7 + 3 pad
#define NSPL    20         // 16 layer-1 edges + 4 layer-2
#define NPTS    524288

// LDS tables built once per block
struct SplineTabs {
    float knots[NSPL][NKNOT];
    float inv1[NSPL][12];  // 1/(t[i+1]-t[i])
    float inv2[NSPL][11];  // 1/(t[i+2]-t[i])
    float inv3[NSPL][10];  // 1/(t[i+3]-t[i])
    float coef[NSPL][9];   // 8 coeffs + c[8]=0 (reference truncates 9th basis col)
    float w0[HID];
    float w1[HID];
    float base;
};

__device__ __forceinline__ float softplusf(float x) {
    return fmaxf(x, 0.0f) + log1pf(expf(-fabsf(x)));
}

// Evaluate clamped cubic B-spline with per-spline LDS tables.
// Matches reference semantics: 0 outside [-1,1), 0 at x==1 (9th basis truncated
// and reference recursion zeroes the x==knots[-1] case anyway).
__device__ __forceinline__ float spline_eval(const SplineTabs& T, int s, float x) {
    bool in_dom = (x >= -1.0f) && (x < 1.0f);   // NaN -> false -> 0, like reference
    if (!in_dom) return 0.0f;

    const float* t = T.knots[s];
    // branchless span search: j in [3,8], t[j] <= x < t[j+1]
    int j = 3;
    j += (x >= t[4]);
    j += (x >= t[5]);
    j += (x >= t[6]);
    j += (x >= t[7]);
    j += (x >= t[8]);

    float l1v = x - t[j];
    float l2v = x - t[j - 1];
    float l3v = x - t[j - 2];
    float r1 = t[j + 1] - x;
    float r2 = t[j + 2] - x;
    float r3 = t[j + 3] - x;

    // de Boor triangle with precomputed reciprocal denominators (all > 0 for valid spans)
    float temp, saved;
    // r = 1
    temp = T.inv1[s][j];
    float N0 = r1 * temp;
    float N1 = l1v * temp;
    // r = 2
    temp = N0 * T.inv2[s][j - 1];
    N0 = r1 * temp;
    saved = l2v * temp;
    temp = N1 * T.inv2[s][j];
    N1 = saved + r2 * temp;
    float N2 = l1v * temp;
    // r = 3
    temp = N0 * T.inv3[s][j - 2];
    N0 = r1 * temp;
    saved = l3v * temp;
    temp = N1 * T.inv3[s][j - 1];
    N1 = saved + r2 * temp;
    saved = l2v * temp;
    temp = N2 * T.inv3[s][j];
    N2 = saved + r3 * temp;
    float N3 = l1v * temp;

    const float* c = T.coef[s];
    return N0 * c[j - 3] + N1 * c[j - 2] + N2 * c[j - 1] + N3 * c[j];
}

__global__ __launch_bounds__(256) void unified_kan_kernel(
    const float* __restrict__ x,             // (N, 4)
    const float* __restrict__ l1_coeffs,     // (16, 8)
    const float* __restrict__ l1_kd,         // (16, 6)
    const float* __restrict__ op_alpha,      // (4, 2)
    const float* __restrict__ gumbel,        // (4, 2)
    const float* __restrict__ l2_coeffs,     // (4, 8)
    const float* __restrict__ l2_kd,         // (4, 6)
    const float* __restrict__ base_offset,   // (1,)
    float* __restrict__ out)                 // (N,)
{
    __shared__ SplineTabs T;
    const int tid = threadIdx.x;

    if (tid < NSPL) {
        const int s = tid;
        const float* deltas;
        const float* cf;
        if (s < HID * IN_DIM) { deltas = l1_kd + s * (GRIDK + 1); cf = l1_coeffs + s * NC; }
        else                  { deltas = l2_kd + (s - HID * IN_DIM) * (GRIDK + 1);
                                cf = l2_coeffs + (s - HID * IN_DIM) * NC; }

        float d[GRIDK + 1];
        float dsum = 0.0f;
        #pragma unroll
        for (int j = 0; j < GRIDK + 1; ++j) { d[j] = softplusf(deltas[j]); dsum += d[j]; }
        float scale = 2.0f / dsum;

        float t[NKNOT];
        t[0] = t[1] = t[2] = t[3] = -1.0f;
        float acc = 0.0f;
        #pragma unroll
        for (int j = 0; j < GRIDK; ++j) { acc += d[j] * scale; t[4 + j] = -1.0f + acc; }
        t[9] = t[10] = t[11] = t[12] = 1.0f;

        #pragma unroll
        for (int i = 0; i < NKNOT; ++i) T.knots[s][i] = t[i];
        #pragma unroll
        for (int i = 0; i < 12; ++i) { float den = t[i + 1] - t[i]; T.inv1[s][i] = (den > 1e-8f) ? 1.0f / den : 0.0f; }
        #pragma unroll
        for (int i = 0; i < 11; ++i) { float den = t[i + 2] - t[i]; T.inv2[s][i] = (den > 1e-8f) ? 1.0f / den : 0.0f; }
        #pragma unroll
        for (int i = 0; i < 10; ++i) { float den = t[i + 3] - t[i]; T.inv3[s][i] = (den > 1e-8f) ? 1.0f / den : 0.0f; }
        #pragma unroll
        for (int i = 0; i < NC; ++i) T.coef[s][i] = cf[i];
        T.coef[s][8] = 0.0f;
    } else if (tid < NSPL + HID) {
        const int h = tid - NSPL;
        float a0 = op_alpha[h * 2 + 0] + gumbel[h * 2 + 0];   // TAU == 1
        float a1 = op_alpha[h * 2 + 1] + gumbel[h * 2 + 1];
        float m = fmaxf(a0, a1);
        float e0 = expf(a0 - m), e1 = expf(a1 - m);
        float inv = 1.0f / (e0 + e1);
        T.w0[h] = e0 * inv;
        T.w1[h] = e1 * inv;
    } else if (tid == NSPL + HID) {
        T.base = base_offset[0];
    }
    __syncthreads();

    const int stride = gridDim.x * blockDim.x;
    for (int i = blockIdx.x * blockDim.x + tid; i < NPTS; i += stride) {
        float4 xv = reinterpret_cast<const float4*>(x)[i];
        float xin[IN_DIM] = {xv.x, xv.y, xv.z, xv.w};

        float acc = T.base;
        #pragma unroll
        for (int h = 0; h < HID; ++h) {
            float sum = 0.0f, prod = 1.0f;
            #pragma unroll
            for (int k = 0; k < IN_DIM; ++k) {
                float v = spline_eval(T, h * IN_DIM + k, xin[k]);
                sum += v;
                prod *= fminf(fmaxf(v, -5.0f), 5.0f);
            }
            float hid = T.w0[h] * sum + T.w1[h] * prod;
            acc += spline_eval(T, HID * IN_DIM + h, hid);
        }
        out[i] = acc;
    }
}

extern "C" void kernel_launch(void* const* d_in, const int* in_sizes, int n_in,
                              void* d_out, int out_size, void* d_ws, size_t ws_size,
                              hipStream_t stream) {
    const float* x         = (const float*)d_in[0];
    const float* l1_coeffs = (const float*)d_in[1];
    const float* l1_kd     = (const float*)d_in[2];
    const float* op_alpha  = (const float*)d_in[3];
    const float* gumbel    = (const float*)d_in[4];
    const float* l2_coeffs = (const float*)d_in[5];
    const float* l2_kd     = (const float*)d_in[6];
    const float* base_off  = (const float*)d_in[7];
    float* out = (float*)d_out;

    const int block = 256;
    const int grid = 1024;   // grid-stride, 2 points/thread; 4 blocks/CU
    unified_kan_kernel<<<grid, block, 0, stream>>>(
        x, l1_coeffs, l1_kd, op_alpha, gumbel, l2_coeffs, l2_kd, base_off, out);
}

// Round 2
// 85.006 us; speedup vs baseline: 1.1362x; 1.1362x over previous
//
#include <hip/hip_runtime.h>
#include <math.h>

#define GRIDK   5
#define DEG     3
#define NC      8          // GRID + DEG
#define IN_DIM  4
#define HID     4
#define NKNOT   13         // 3 pad + 7 interior(+ends) + 3 pad
#define NSPL    20         // 16 layer-1 edges + 4 layer-2
#define NPTS    524288
#define NSPAN   6          // valid spans j in [3,8]

__device__ __forceinline__ float softplusf(float x) {
    return fmaxf(x, 0.0f) + log1pf(expf(-fabsf(x)));
}

// Per-spline, per-span cubic in u = x - t_j (shifted local power basis):
//   v(x) = c0 + c1*u + c2*u^2 + c3*u^3   for x in [t_j, t_{j+1})
// Built once per block from the same masked de Boor recursion the reference
// uses (den > 1e-8 masks identical), so only fp-reordering differences remain.

__global__ __launch_bounds__(256) void unified_kan_kernel(
    const float* __restrict__ x,             // (N, 4)
    const float* __restrict__ l1_coeffs,     // (16, 8)
    const float* __restrict__ l1_kd,         // (16, 6)
    const float* __restrict__ op_alpha,      // (4, 2)
    const float* __restrict__ gumbel,        // (4, 2)
    const float* __restrict__ l2_coeffs,     // (4, 8)
    const float* __restrict__ l2_kd,         // (4, 6)
    const float* __restrict__ base_offset,   // (1,)
    float* __restrict__ out)                 // (N,)
{
    __shared__ float4 polyS[NSPL * NSPAN];   // [s*6 + (j-3)] : {c0,c1,c2,c3}
    __shared__ float4 kn4S[NSPL];            // {t4,t5,t6,t7}
    __shared__ float  kn8S[NSPL];            // t8
    __shared__ float  w0S[HID], w1S[HID], baseS;

    const int tid = threadIdx.x;

    if (tid < NSPL * NSPAN) {
        const int s  = tid / NSPAN;
        const int jj = 3 + (tid % NSPAN);    // span index in [3,8]

        const float* deltas = (s < HID * IN_DIM)
            ? l1_kd + s * (GRIDK + 1)
            : l2_kd + (s - HID * IN_DIM) * (GRIDK + 1);
        const float* cf = (s < HID * IN_DIM)
            ? l1_coeffs + s * NC
            : l2_coeffs + (s - HID * IN_DIM) * NC;

        // knots (redundant x6 per spline — trivial cost)
        float d[GRIDK + 1];
        float dsum = 0.0f;
        #pragma unroll
        for (int k = 0; k < GRIDK + 1; ++k) { d[k] = softplusf(deltas[k]); dsum += d[k]; }
        const float scale = 2.0f / dsum;

        float t[NKNOT];
        t[0] = t[1] = t[2] = t[3] = -1.0f;
        float acc = 0.0f;
        #pragma unroll
        for (int k = 0; k < GRIDK; ++k) { acc += d[k] * scale; t[4 + k] = -1.0f + acc; }
        t[9] = t[10] = t[11] = t[12] = 1.0f;

        // de Boor in u = x - t[jj] polynomial form.
        // P[m][k] = coeff of u^k in N_{jj-d+m, d}, m in [0,d]
        float P[4][4];
        #pragma unroll
        for (int m = 0; m < 4; ++m)
            #pragma unroll
            for (int k = 0; k < 4; ++k) P[m][k] = 0.0f;
        P[0][0] = 1.0f;   // degree 0: N_jj = 1 on the span

        #pragma unroll
        for (int dd = 1; dd <= 3; ++dd) {
            float NP[4][4];
            #pragma unroll
            for (int m = 0; m < 4; ++m)
                #pragma unroll
                for (int k = 0; k < 4; ++k) NP[m][k] = 0.0f;

            for (int m = 0; m <= dd; ++m) {
                const int i = jj - dd + m;
                if (m >= 1) {
                    // (x - t_i)/(t_{i+dd} - t_i) * N_{i,dd-1}
                    const float den = t[i + dd] - t[i];
                    if (den > 1e-8f) {
                        const float inv = 1.0f / den;
                        const float a = (t[jj] - t[i]) * inv;   // (u + (t_jj - t_i)) * inv
                        #pragma unroll
                        for (int k = 0; k < 4; ++k) NP[m][k] += a * P[m - 1][k];
                        #pragma unroll
                        for (int k = 1; k < 4; ++k) NP[m][k] += inv * P[m - 1][k - 1];
                    }
                }
                if (m <= dd - 1) {
                    // (t_{i+dd+1} - x)/(t_{i+dd+1} - t_{i+1}) * N_{i+1,dd-1}
                    const float den = t[i + dd + 1] - t[i + 1];
                    if (den > 1e-8f) {
                        const float inv = 1.0f / den;
                        const float a = (t[i + dd + 1] - t[jj]) * inv;  // ((t..) - t_jj - u) * inv
                        #pragma unroll
                        for (int k = 0; k < 4; ++k) NP[m][k] += a * P[m][k];
                        #pragma unroll
                        for (int k = 1; k < 4; ++k) NP[m][k] -= inv * P[m][k - 1];
                    }
                }
            }
            #pragma unroll
            for (int m = 0; m < 4; ++m)
                #pragma unroll
                for (int k = 0; k < 4; ++k) P[m][k] = NP[m][k];
        }

        // combine with coefficients; basis cols jj-3..jj; col 8 truncated -> 0
        float4 o = make_float4(0.f, 0.f, 0.f, 0.f);
        #pragma unroll
        for (int m = 0; m < 4; ++m) {
            const int i = jj - 3 + m;
            const float c = (i < NC) ? cf[i] : 0.0f;
            o.x += c * P[m][0];
            o.y += c * P[m][1];
            o.z += c * P[m][2];
            o.w += c * P[m][3];
        }
        polyS[s * NSPAN + (jj - 3)] = o;

        if ((tid % NSPAN) == 0) {
            kn4S[s] = make_float4(t[4], t[5], t[6], t[7]);
            kn8S[s] = t[8];
        }
    } else if (tid < NSPL * NSPAN + HID) {
        const int h = tid - NSPL * NSPAN;
        float a0 = op_alpha[h * 2 + 0] + gumbel[h * 2 + 0];   // TAU == 1
        float a1 = op_alpha[h * 2 + 1] + gumbel[h * 2 + 1];
        float m = fmaxf(a0, a1);
        float e0 = expf(a0 - m), e1 = expf(a1 - m);
        float inv = 1.0f / (e0 + e1);
        w0S[h] = e0 * inv;
        w1S[h] = e1 * inv;
    } else if (tid == NSPL * NSPAN + HID) {
        baseS = base_offset[0];
    }
    __syncthreads();

    // spline evaluator: kn values passed in registers (loaded once per spline)
    auto eval = [&](int s, float4 kn, float k8, float xv) -> float {
        const bool c4 = xv >= kn.x;
        const bool c5 = xv >= kn.y;
        const bool c6 = xv >= kn.z;
        const bool c7 = xv >= kn.w;
        const bool c8 = xv >= k8;
        const int j = (int)c4 + (int)c5 + (int)c6 + (int)c7 + (int)c8;  // 0..5 = span-3
        float tj = -1.0f;
        tj = c4 ? kn.x : tj;
        tj = c5 ? kn.y : tj;
        tj = c6 ? kn.z : tj;
        tj = c7 ? kn.w : tj;
        tj = c8 ? k8   : tj;
        const float4 c = polyS[s * NSPAN + j];
        const float u = xv - tj;
        float v = fmaf(fmaf(fmaf(c.w, u, c.z), u, c.y), u, c.x);
        const bool dom = (xv >= -1.0f) && (xv < 1.0f);
        return dom ? v : 0.0f;
    };

    // two points per thread, coalesced stride
    const int gid = blockIdx.x * blockDim.x + tid;           // 0..262143
    const int i0 = gid;
    const int i1 = gid + (NPTS / 2);

    const float4 xa = reinterpret_cast<const float4*>(x)[i0];
    const float4 xb = reinterpret_cast<const float4*>(x)[i1];
    const float x0[IN_DIM] = {xa.x, xa.y, xa.z, xa.w};
    const float x1[IN_DIM] = {xb.x, xb.y, xb.z, xb.w};

    float acc0 = baseS, acc1 = baseS;

    #pragma unroll
    for (int h = 0; h < HID; ++h) {
        float sum0 = 0.f, sum1 = 0.f, prod0 = 1.f, prod1 = 1.f;
        #pragma unroll
        for (int k = 0; k < IN_DIM; ++k) {
            const int s = h * IN_DIM + k;
            const float4 kn = kn4S[s];
            const float  k8 = kn8S[s];
            const float v0 = eval(s, kn, k8, x0[k]);
            const float v1 = eval(s, kn, k8, x1[k]);
            sum0 += v0; sum1 += v1;
            prod0 *= fminf(fmaxf(v0, -5.0f), 5.0f);
            prod1 *= fminf(fmaxf(v1, -5.0f), 5.0f);
        }
        const float w0 = w0S[h], w1 = w1S[h];
        const float hid0 = w0 * sum0 + w1 * prod0;
        const float hid1 = w0 * sum1 + w1 * prod1;
        const int s2 = HID * IN_DIM + h;
        const float4 kn = kn4S[s2];
        const float  k8 = kn8S[s2];
        acc0 += eval(s2, kn, k8, hid0);
        acc1 += eval(s2, kn, k8, hid1);
    }

    out[i0] = acc0;
    out[i1] = acc1;
}

extern "C" void kernel_launch(void* const* d_in, const int* in_sizes, int n_in,
                              void* d_out, int out_size, void* d_ws, size_t ws_size,
                              hipStream_t stream) {
    const float* x         = (const float*)d_in[0];
    const float* l1_coeffs = (const float*)d_in[1];
    const float* l1_kd     = (const float*)d_in[2];
    const float* op_alpha  = (const float*)d_in[3];
    const float* gumbel    = (const float*)d_in[4];
    const float* l2_coeffs = (const float*)d_in[5];
    const float* l2_kd     = (const float*)d_in[6];
    const float* base_off  = (const float*)d_in[7];
    float* out = (float*)d_out;

    const int block = 256;
    const int grid = NPTS / (block * 2);   // 1024 blocks, 2 points/thread, 4 blocks/CU
    unified_kan_kernel<<<grid, block, 0, stream>>>(
        x, l1_coeffs, l1_kd, op_alpha, gumbel, l2_coeffs, l2_kd, base_off, out);
}